// Round 5
// baseline (268.784 us; speedup 1.0000x reference)
//
#include <hip/hip_runtime.h>
#include <hip/hip_bf16.h>

#define EPSV 1e-5f

// ---------------- K1: 4x4 avg-pool + GroupNorm(32) + SiLU, and bias-init z0 ----------------
// grid 512 = B(16) x G(32), block 256 (one thread per pooled pixel)
__global__ __launch_bounds__(256) void k1_pool_gn1(
    const float* __restrict__ x, const float* __restrict__ g1, const float* __restrict__ b1,
    const float* __restrict__ b_conv1, float* __restrict__ a1, float* __restrict__ z0)
{
    const int blk = blockIdx.x;
    const int b = blk >> 5, g = blk & 31;
    const int t = threadIdx.x;
    const int ph = t >> 4, pw = t & 15;

    float v[10];
    float s = 0.f, ss = 0.f;
#pragma unroll
    for (int k = 0; k < 10; ++k) {
        const int c = g * 10 + k;
        const float* base = x + (((size_t)(b * 320 + c)) * 64 + ph * 4) * 64 + pw * 4;
        float acc = 0.f;
#pragma unroll
        for (int i = 0; i < 4; ++i) {
            const float4 r = *reinterpret_cast<const float4*>(base + i * 64);
            acc += r.x + r.y + r.z + r.w;
        }
        v[k] = acc * (1.f / 16.f);
        s += v[k];
        ss += v[k] * v[k];
    }

    __shared__ float rs[4], rss[4];
#pragma unroll
    for (int off = 32; off; off >>= 1) {
        s += __shfl_down(s, off);
        ss += __shfl_down(ss, off);
    }
    const int wid = t >> 6, lane = t & 63;
    if (lane == 0) { rs[wid] = s; rss[wid] = ss; }
    __syncthreads();
    const float S = rs[0] + rs[1] + rs[2] + rs[3];
    const float SS = rss[0] + rss[1] + rss[2] + rss[3];
    const float mean = S * (1.f / 2560.f);
    const float var = SS * (1.f / 2560.f) - mean * mean;
    const float inv = rsqrtf(var + EPSV);

#pragma unroll
    for (int k = 0; k < 10; ++k) {
        const int c = g * 10 + k;
        const float xn = (v[k] - mean) * inv * g1[c] + b1[c];
        const float y = xn / (1.f + __expf(-xn));
        a1[((size_t)(b * 320 + c)) * 256 + t] = y;
    }

    // init z0 with conv1 bias (z0 gets atomicAdd'ed by K2)
    const int idx = blk * 256 + t;
    if (idx < 16 * 8 * 256) z0[idx] = b_conv1[(idx >> 8) & 7];
}

// ---------------- K2: conv3x3 320->8 on 16x16, chunked over channels, atomic accumulate ----------------
// grid 256 = B(16) x chunks(16 of 20 channels), block 256 (one thread per pixel)
__global__ __launch_bounds__(256) void k2_conv1(
    const float* __restrict__ a1, const float* __restrict__ w1, float* __restrict__ z0)
{
    const int b = blockIdx.x >> 4, ch = blockIdx.x & 15;
    const int t = threadIdx.x;
    const int ph = t >> 4, pw = t & 15;
    const int c0 = ch * 20;

    __shared__ __align__(16) float tiles[20 * 256];
    __shared__ float lw[8 * 20 * 9];

    {
        const float4* src = reinterpret_cast<const float4*>(a1 + (size_t)(b * 320 + c0) * 256);
        float4* dst = reinterpret_cast<float4*>(tiles);
        for (int i = t; i < 1280; i += 256) dst[i] = src[i];
    }
    for (int i = t; i < 1440; i += 256) {
        const int o = i / 180, rem = i % 180, cc = rem / 9, k = rem % 9;
        lw[i] = w1[(o * 320 + c0 + cc) * 9 + k];
    }
    __syncthreads();

    float acc[8] = {0.f, 0.f, 0.f, 0.f, 0.f, 0.f, 0.f, 0.f};
    for (int cc = 0; cc < 20; ++cc) {
        const float* tp = &tiles[cc * 256];
#pragma unroll
        for (int ky = 0; ky < 3; ++ky) {
            const int yy = ph + ky - 1;
            if ((unsigned)yy > 15u) continue;
#pragma unroll
            for (int kx = 0; kx < 3; ++kx) {
                const int xx = pw + kx - 1;
                if ((unsigned)xx > 15u) continue;
                const float val = tp[yy * 16 + xx];
                const int wi = cc * 9 + ky * 3 + kx;
#pragma unroll
                for (int o = 0; o < 8; ++o) acc[o] += lw[o * 180 + wi] * val;
            }
        }
    }
    float* zp = z0 + (size_t)b * 2048 + t;
#pragma unroll
    for (int o = 0; o < 8; ++o) atomicAdd(zp + o * 256, acc[o]);
}

// ---------------- K3f: fully fused middle block ----------------
// grid 16 = B, block 1024 (16 waves). Attention: 1024 (head,pixel) rows, one per
// thread, k/v broadcast from LDS. GN stats via 16-wave reductions. No global
// round-trips between qkv / attention / post phases.
__global__ __launch_bounds__(1024) void k3f_middle(
    const float* __restrict__ z0,
    const float* __restrict__ ga, const float* __restrict__ ba,
    const float* __restrict__ w_qkv, const float* __restrict__ b_qkv,
    const float* __restrict__ w_proj, const float* __restrict__ b_proj,
    const float* __restrict__ ln_g, const float* __restrict__ ln_b,
    const float* __restrict__ w_fc1, const float* __restrict__ b_fc1,
    const float* __restrict__ w_fc2, const float* __restrict__ b_fc2,
    const float* __restrict__ g2, const float* __restrict__ b2,
    float* __restrict__ a2)
{
    const int b = blockIdx.x, t = threadIdx.x;
    const int wv = t >> 6, lane = t & 63;   // 16 waves

    __shared__ __align__(16) float zsh[2048];     // [c*256+n]
    __shared__ float2 qsh[4 * 256];               // [h*256+n], pre-scaled q
    __shared__ float4 kvp[4 * 256];               // [h*256+m] = (k0,k1,v0,v1)
    __shared__ float aos[256 * 8];                // [n*8+c] attention out
    __shared__ float part[16][2];
    __shared__ float stats[16];

    if (t < 512)
        reinterpret_cast<float4*>(zsh)[t] =
            reinterpret_cast<const float4*>(z0 + (size_t)b * 2048)[t];
    __syncthreads();

    // GN_a stats: wave wv handles channel wv>>1, half (wv&1) of its 256 pixels
    {
        const int c = wv >> 1, base = (wv & 1) * 128;
        const float v0 = zsh[c * 256 + base + lane];
        const float v1 = zsh[c * 256 + base + 64 + lane];
        float s = v0 + v1, ss = v0 * v0 + v1 * v1;
#pragma unroll
        for (int off = 32; off; off >>= 1) {
            s += __shfl_down(s, off);
            ss += __shfl_down(ss, off);
        }
        if (lane == 0) { part[wv][0] = s; part[wv][1] = ss; }
    }
    __syncthreads();
    if (t < 8) {
        const float S = part[2 * t][0] + part[2 * t + 1][0];
        const float SS = part[2 * t][1] + part[2 * t + 1][1];
        const float m = S * (1.f / 256.f);
        const float vv = SS * (1.f / 256.f) - m * m;
        stats[2 * t] = m;
        stats[2 * t + 1] = rsqrtf(vv + EPSV);
    }
    __syncthreads();

    // qkv projection (threads 0..255, one pixel each)
    if (t < 256) {
        float gn[8];
#pragma unroll
        for (int c = 0; c < 8; ++c)
            gn[c] = (zsh[c * 256 + t] - stats[2 * c]) * stats[2 * c + 1] * ga[c] + ba[c];
        float qv[24];
#pragma unroll
        for (int o = 0; o < 24; ++o) {
            float acc = b_qkv[o];
#pragma unroll
            for (int c = 0; c < 8; ++c) acc += w_qkv[o * 8 + c] * gn[c];
            qv[o] = acc;
        }
        const float lscale = 0.70710678118654752f * 1.44269504088896341f; // dh^-0.5 * log2e
#pragma unroll
        for (int h = 0; h < 4; ++h) {
            qsh[h * 256 + t] = make_float2(qv[2 * h] * lscale, qv[2 * h + 1] * lscale);
            kvp[h * 256 + t] = make_float4(qv[8 + 2 * h], qv[8 + 2 * h + 1],
                                           qv[16 + 2 * h], qv[16 + 2 * h + 1]);
        }
    }
    __syncthreads();

    // attention: row = (h = t>>8, n = t&255); max-free softmax (scores bounded)
    {
        const int n = t & 255;
        const float2 q = qsh[t];
        const float4* kp = &kvp[t & ~255];
        float l = 0.f, o0 = 0.f, o1 = 0.f;
#pragma unroll 8
        for (int m = 0; m < 256; ++m) {
            const float4 kvv = kp[m];
            const float e = __builtin_exp2f(q.x * kvv.x + q.y * kvv.y);
            l += e;
            o0 += e * kvv.z;
            o1 += e * kvv.w;
        }
        const float rl = 1.f / l;
        const int h = t >> 8;
        aos[n * 8 + 2 * h] = o0 * rl;
        aos[n * 8 + 2 * h + 1] = o1 * rl;
    }
    __syncthreads();

    // post: proj+res, LN, MLP+res (threads 0..255); z2 back into zsh for GN2
    if (t < 256) {
        float z1[8];
#pragma unroll
        for (int o = 0; o < 8; ++o) {
            float acc = b_proj[o];
#pragma unroll
            for (int c = 0; c < 8; ++c) acc += w_proj[o * 8 + c] * aos[t * 8 + c];
            z1[o] = zsh[o * 256 + t] + acc;
        }
        float mu = 0.f;
#pragma unroll
        for (int c = 0; c < 8; ++c) mu += z1[c];
        mu *= (1.f / 8.f);
        float var = 0.f;
#pragma unroll
        for (int c = 0; c < 8; ++c) { const float d = z1[c] - mu; var += d * d; }
        var *= (1.f / 8.f);
        const float linv = rsqrtf(var + EPSV);
        float ln[8];
#pragma unroll
        for (int c = 0; c < 8; ++c) ln[c] = (z1[c] - mu) * linv * ln_g[c] + ln_b[c];

        float hg[16];
#pragma unroll
        for (int o = 0; o < 16; ++o) {
            float hv = b_fc1[o];
#pragma unroll
            for (int c = 0; c < 8; ++c) hv += w_fc1[o * 8 + c] * ln[c];
            hg[o] = 0.5f * hv * (1.f + erff(hv * 0.70710678f));
        }
        float z2[8];
#pragma unroll
        for (int c = 0; c < 8; ++c) {
            float acc = b_fc2[c];
#pragma unroll
            for (int o = 0; o < 16; ++o) acc += w_fc2[c * 16 + o] * hg[o];
            z2[c] = z1[c] + acc;
        }
        // overwrite zsh with z2 (old zsh no longer needed)
        __syncthreads();
#pragma unroll
        for (int c = 0; c < 8; ++c) zsh[c * 256 + t] = z2[c];
    } else {
        __syncthreads();
    }
    __syncthreads();

    // GN2 stats on pre-upsample map (repeat preserves mean/var)
    {
        const int c = wv >> 1, base = (wv & 1) * 128;
        const float v0 = zsh[c * 256 + base + lane];
        const float v1 = zsh[c * 256 + base + 64 + lane];
        float s = v0 + v1, ss = v0 * v0 + v1 * v1;
#pragma unroll
        for (int off = 32; off; off >>= 1) {
            s += __shfl_down(s, off);
            ss += __shfl_down(ss, off);
        }
        if (lane == 0) { part[wv][0] = s; part[wv][1] = ss; }
    }
    __syncthreads();
    if (t < 8) {
        const float S = part[2 * t][0] + part[2 * t + 1][0];
        const float SS = part[2 * t][1] + part[2 * t + 1][1];
        const float m = S * (1.f / 256.f);
        const float vv = SS * (1.f / 256.f) - m * m;
        stats[2 * t] = m;
        stats[2 * t + 1] = rsqrtf(vv + EPSV);
    }
    __syncthreads();

    // SiLU(GN2) -> a2, 2 consecutive elements per thread (same channel)
    {
        const int i0 = t * 2;
        const int c = i0 >> 8;
        const float m = stats[2 * c], inv = stats[2 * c + 1];
        const float gg = g2[c], bb = b2[c];
        const float x0 = (zsh[i0] - m) * inv * gg + bb;
        const float x1 = (zsh[i0 + 1] - m) * inv * gg + bb;
        const float y0 = x0 / (1.f + __expf(-x0));
        const float y1 = x1 / (1.f + __expf(-x1));
        reinterpret_cast<float2*>(a2 + (size_t)b * 2048)[t] = make_float2(y0, y1);
    }
}

// ---------------- K4: upsample-on-the-fly conv3x3 8->320 on 64x64 ----------------
// Upsampled input is piecewise-constant over 4x4 cells: the 16 outputs per
// cell take only 9 distinct values. ~25 FMA + ~24 adds per channel vs 144 FMA.
// grid (320, 16) = (out-channel, batch), block 256 (one thread per 4x4 cell)
__global__ __launch_bounds__(256) void k4_conv2(
    const float* __restrict__ a2, const float* __restrict__ w2,
    const float* __restrict__ bc2, float* __restrict__ out)
{
    const int o = blockIdx.x, b = blockIdx.y, t = threadIdx.x;
    __shared__ float A[8 * 324];   // (8, 18, 18) zero-halo padded pooled map
    __shared__ float wsh[72];

    for (int i = t; i < 2592; i += 256) A[i] = 0.f;
    if (t < 72) wsh[t] = w2[o * 72 + t];
    __syncthreads();
    for (int i = t; i < 2048; i += 256) {
        const int c = i >> 8, y = (i >> 4) & 15, x = i & 15;
        A[c * 324 + (y + 1) * 18 + (x + 1)] = a2[(size_t)b * 2048 + i];
    }
    __syncthreads();

    const int cy = t >> 4, cx = t & 15;
    const float bias = bc2[o];
    float acc[3][3];
#pragma unroll
    for (int r = 0; r < 3; ++r)
#pragma unroll
        for (int s = 0; s < 3; ++s) acc[r][s] = bias;

    const float* Abase = &A[cy * 18 + cx];
#pragma unroll
    for (int c = 0; c < 8; ++c) {
        const float C00 = Abase[c * 324 + 0 * 18 + 0], C01 = Abase[c * 324 + 0 * 18 + 1], C02 = Abase[c * 324 + 0 * 18 + 2];
        const float C10 = Abase[c * 324 + 1 * 18 + 0], C11 = Abase[c * 324 + 1 * 18 + 1], C12 = Abase[c * 324 + 1 * 18 + 2];
        const float C20 = Abase[c * 324 + 2 * 18 + 0], C21 = Abase[c * 324 + 2 * 18 + 1], C22 = Abase[c * 324 + 2 * 18 + 2];

        const float k0 = wsh[c * 9 + 0], k1 = wsh[c * 9 + 1], k2 = wsh[c * 9 + 2];
        const float k3 = wsh[c * 9 + 3], k4 = wsh[c * 9 + 4], k5 = wsh[c * 9 + 5];
        const float k6 = wsh[c * 9 + 6], k7 = wsh[c * 9 + 7], k8 = wsh[c * 9 + 8];

        const float q12x = k3 + k6, q12y = k4 + k7, q12z = k5 + k8;
        const float q01x = k0 + k3, q01y = k1 + k4, q01z = k2 + k5;
        const float qax = q12x + k0, qay = q12y + k1, qaz = q12z + k2;

        const float r0_c12 = k1 + k2,      r0_c012 = r0_c12 + k0,     r0_c01 = k0 + k1;
        const float q12_c12 = q12y + q12z, q12_c012 = q12_c12 + q12x, q12_c01 = q12x + q12y;
        const float qa_c12 = qay + qaz,    qa_c012 = qa_c12 + qax,    qa_c01 = qax + qay;
        const float q01_c12 = q01y + q01z, q01_c012 = q01_c12 + q01x, q01_c01 = q01x + q01y;
        const float r2_c12 = k7 + k8,      r2_c012 = r2_c12 + k6,     r2_c01 = k6 + k7;

        acc[0][0] += k0 * C00 + r0_c12 * C01 + q12x * C10 + q12_c12 * C11;
        acc[0][1] += r0_c012 * C01 + q12_c012 * C11;
        acc[0][2] += r0_c01 * C01 + k2 * C02 + q12_c01 * C11 + q12z * C12;
        acc[1][0] += qax * C10 + qa_c12 * C11;
        acc[1][1] += qa_c012 * C11;
        acc[1][2] += qa_c01 * C11 + qaz * C12;
        acc[2][0] += q01x * C10 + q01_c12 * C11 + k6 * C20 + r2_c12 * C21;
        acc[2][1] += q01_c012 * C11 + r2_c012 * C21;
        acc[2][2] += q01_c01 * C11 + q01z * C12 + r2_c01 * C21 + k8 * C22;
    }

    const size_t base = ((size_t)(b * 320 + o)) * 4096;
    const int rowmap[4] = {0, 1, 1, 2};
#pragma unroll
    for (int py = 0; py < 4; ++py) {
        const int r = rowmap[py];
        const float4 v = make_float4(acc[r][0], acc[r][1], acc[r][1], acc[r][2]);
        *reinterpret_cast<float4*>(out + base + (cy * 4 + py) * 64 + cx * 4) = v;
    }
}

extern "C" void kernel_launch(void* const* d_in, const int* in_sizes, int n_in,
                              void* d_out, int out_size, void* d_ws, size_t ws_size,
                              hipStream_t stream) {
    const float* x       = (const float*)d_in[0];
    const float* g1      = (const float*)d_in[1];
    const float* b1      = (const float*)d_in[2];
    const float* w_conv1 = (const float*)d_in[3];
    const float* b_conv1 = (const float*)d_in[4];
    const float* ga      = (const float*)d_in[5];
    const float* ba      = (const float*)d_in[6];
    const float* w_qkv   = (const float*)d_in[7];
    const float* b_qkv   = (const float*)d_in[8];
    const float* w_proj  = (const float*)d_in[9];
    const float* b_proj  = (const float*)d_in[10];
    const float* ln_g    = (const float*)d_in[11];
    const float* ln_b    = (const float*)d_in[12];
    const float* w_fc1   = (const float*)d_in[13];
    const float* b_fc1   = (const float*)d_in[14];
    const float* w_fc2   = (const float*)d_in[15];
    const float* b_fc2   = (const float*)d_in[16];
    const float* g2      = (const float*)d_in[17];
    const float* b2      = (const float*)d_in[18];
    const float* w_conv2 = (const float*)d_in[19];
    const float* b_conv2 = (const float*)d_in[20];

    float* a1 = (float*)d_ws;             // 1,310,720 floats
    float* z0 = a1 + 1310720;             //    32,768
    float* a2 = z0 + 32768;               //    32,768
    float* out = (float*)d_out;

    k1_pool_gn1<<<512, 256, 0, stream>>>(x, g1, b1, b_conv1, a1, z0);
    k2_conv1<<<256, 256, 0, stream>>>(a1, w_conv1, z0);
    k3f_middle<<<16, 1024, 0, stream>>>(z0, ga, ba, w_qkv, b_qkv, w_proj, b_proj,
                                        ln_g, ln_b, w_fc1, b_fc1, w_fc2, b_fc2, g2, b2, a2);
    k4_conv2<<<dim3(320, 16), 256, 0, stream>>>(a2, w_conv2, b_conv2, out);
}

// Round 6
// 254.169 us; speedup vs baseline: 1.0575x; 1.0575x over previous
//
#include <hip/hip_runtime.h>
#include <hip/hip_bf16.h>

#define EPSV 1e-5f

// ---------------- K1: 4x4 avg-pool + GroupNorm(32) + SiLU, and bias-init z0 ----------------
// grid 512 = B(16) x G(32), block 256 (one thread per pooled pixel)
__global__ __launch_bounds__(256) void k1_pool_gn1(
    const float* __restrict__ x, const float* __restrict__ g1, const float* __restrict__ b1,
    const float* __restrict__ b_conv1, float* __restrict__ a1, float* __restrict__ z0)
{
    const int blk = blockIdx.x;
    const int b = blk >> 5, g = blk & 31;
    const int t = threadIdx.x;
    const int ph = t >> 4, pw = t & 15;

    float v[10];
    float s = 0.f, ss = 0.f;
#pragma unroll
    for (int k = 0; k < 10; ++k) {
        const int c = g * 10 + k;
        const float* base = x + (((size_t)(b * 320 + c)) * 64 + ph * 4) * 64 + pw * 4;
        float acc = 0.f;
#pragma unroll
        for (int i = 0; i < 4; ++i) {
            const float4 r = *reinterpret_cast<const float4*>(base + i * 64);
            acc += r.x + r.y + r.z + r.w;
        }
        v[k] = acc * (1.f / 16.f);
        s += v[k];
        ss += v[k] * v[k];
    }

    __shared__ float rs[4], rss[4];
#pragma unroll
    for (int off = 32; off; off >>= 1) {
        s += __shfl_down(s, off);
        ss += __shfl_down(ss, off);
    }
    const int wid = t >> 6, lane = t & 63;
    if (lane == 0) { rs[wid] = s; rss[wid] = ss; }
    __syncthreads();
    const float S = rs[0] + rs[1] + rs[2] + rs[3];
    const float SS = rss[0] + rss[1] + rss[2] + rss[3];
    const float mean = S * (1.f / 2560.f);
    const float var = SS * (1.f / 2560.f) - mean * mean;
    const float inv = rsqrtf(var + EPSV);

#pragma unroll
    for (int k = 0; k < 10; ++k) {
        const int c = g * 10 + k;
        const float xn = (v[k] - mean) * inv * g1[c] + b1[c];
        const float y = xn / (1.f + __expf(-xn));
        a1[((size_t)(b * 320 + c)) * 256 + t] = y;
    }

    // init z0 with conv1 bias (z0 gets atomicAdd'ed by K2)
    const int idx = blk * 256 + t;
    if (idx < 16 * 8 * 256) z0[idx] = b_conv1[(idx >> 8) & 7];
}

// ---------------- K2: conv3x3 320->8 on 16x16, chunked over channels, atomic accumulate ----------------
// grid 256 = B(16) x chunks(16 of 20 channels), block 256 (one thread per pixel)
__global__ __launch_bounds__(256) void k2_conv1(
    const float* __restrict__ a1, const float* __restrict__ w1, float* __restrict__ z0)
{
    const int b = blockIdx.x >> 4, ch = blockIdx.x & 15;
    const int t = threadIdx.x;
    const int ph = t >> 4, pw = t & 15;
    const int c0 = ch * 20;

    __shared__ __align__(16) float tiles[20 * 256];
    __shared__ float lw[8 * 20 * 9];

    {
        const float4* src = reinterpret_cast<const float4*>(a1 + (size_t)(b * 320 + c0) * 256);
        float4* dst = reinterpret_cast<float4*>(tiles);
        for (int i = t; i < 1280; i += 256) dst[i] = src[i];
    }
    for (int i = t; i < 1440; i += 256) {
        const int o = i / 180, rem = i % 180, cc = rem / 9, k = rem % 9;
        lw[i] = w1[(o * 320 + c0 + cc) * 9 + k];
    }
    __syncthreads();

    float acc[8] = {0.f, 0.f, 0.f, 0.f, 0.f, 0.f, 0.f, 0.f};
    for (int cc = 0; cc < 20; ++cc) {
        const float* tp = &tiles[cc * 256];
#pragma unroll
        for (int ky = 0; ky < 3; ++ky) {
            const int yy = ph + ky - 1;
            if ((unsigned)yy > 15u) continue;
#pragma unroll
            for (int kx = 0; kx < 3; ++kx) {
                const int xx = pw + kx - 1;
                if ((unsigned)xx > 15u) continue;
                const float val = tp[yy * 16 + xx];
                const int wi = cc * 9 + ky * 3 + kx;
#pragma unroll
                for (int o = 0; o < 8; ++o) acc[o] += lw[o * 180 + wi] * val;
            }
        }
    }
    float* zp = z0 + (size_t)b * 2048 + t;
#pragma unroll
    for (int o = 0; o < 8; ++o) atomicAdd(zp + o * 256, acc[o]);
}

// ---------------- K3a: GN(8) + qkv projection; writes scaled q and packed k/v ----------------
// grid 16 = B, block 256 (one thread per pixel n)
__global__ __launch_bounds__(256) void k3a_qkv(
    const float* __restrict__ z0,
    const float* __restrict__ ga, const float* __restrict__ ba,
    const float* __restrict__ w_qkv, const float* __restrict__ b_qkv,
    float2* __restrict__ qs, float4* __restrict__ kv)
{
    const int b = blockIdx.x, t = threadIdx.x;
    const int wid = t >> 6, lane = t & 63;

    __shared__ float zsh[8][256];
    __shared__ float stats[16];

#pragma unroll
    for (int c = 0; c < 8; ++c) zsh[c][t] = z0[(size_t)b * 2048 + c * 256 + t];
    __syncthreads();

#pragma unroll
    for (int cc = 0; cc < 2; ++cc) {
        const int c = wid * 2 + cc;
        const float a0 = zsh[c][lane], a1v = zsh[c][lane + 64], a2v = zsh[c][lane + 128], a3v = zsh[c][lane + 192];
        float s = a0 + a1v + a2v + a3v;
        float ss = a0 * a0 + a1v * a1v + a2v * a2v + a3v * a3v;
#pragma unroll
        for (int off = 32; off; off >>= 1) {
            s += __shfl_down(s, off);
            ss += __shfl_down(ss, off);
        }
        if (lane == 0) {
            const float m = s * (1.f / 256.f);
            const float vv = ss * (1.f / 256.f) - m * m;
            stats[2 * c] = m;
            stats[2 * c + 1] = rsqrtf(vv + EPSV);
        }
    }
    __syncthreads();

    float gn[8];
#pragma unroll
    for (int c = 0; c < 8; ++c) gn[c] = (zsh[c][t] - stats[2 * c]) * stats[2 * c + 1] * ga[c] + ba[c];
    float qv[24];
#pragma unroll
    for (int o = 0; o < 24; ++o) {
        float acc = b_qkv[o];
#pragma unroll
        for (int c = 0; c < 8; ++c) acc += w_qkv[o * 8 + c] * gn[c];
        qv[o] = acc;
    }
    // q pre-scaled by dh^-0.5 * log2(e) so attention inner loop is dot+exp2
    const float lscale = 0.70710678118654752f * 1.44269504088896341f;
#pragma unroll
    for (int h = 0; h < 4; ++h) {
        qs[(b * 4 + h) * 256 + t] = make_float2(qv[2 * h] * lscale, qv[2 * h + 1] * lscale);
        kv[(b * 4 + h) * 256 + t] = make_float4(qv[8 + 2 * h], qv[8 + 2 * h + 1], qv[16 + 2 * h], qv[16 + 2 * h + 1]);
    }
}

// ---------------- K3b: attention (max-free softmax; scores bounded |s|<~3) ----------------
// grid 256 = B(16) x H(4) x ntile(4); block 256 = 64 pixels x 4 m-quarters
__global__ __launch_bounds__(256) void k3b_attn(
    const float2* __restrict__ qs, const float4* __restrict__ kv,
    float* __restrict__ aout)
{
    const int blk = blockIdx.x;
    const int tile = blk & 3, h = (blk >> 2) & 3, b = blk >> 4;
    const int t = threadIdx.x;
    const int nl = t & 63, qr = t >> 6;
    const int bh = b * 4 + h;

    __shared__ float4 kvs[256];
    __shared__ float red[4][64][3];

    kvs[t] = kv[bh * 256 + t];
    __syncthreads();

    const int n = tile * 64 + nl;
    const float2 q = qs[bh * 256 + n];

    float l = 0.f, o0 = 0.f, o1 = 0.f;
    const float4* kp = &kvs[qr * 64];
#pragma unroll 16
    for (int i = 0; i < 64; ++i) {
        const float4 kvv = kp[i];
        const float e = __builtin_exp2f(q.x * kvv.x + q.y * kvv.y);
        l += e;
        o0 += e * kvv.z;
        o1 += e * kvv.w;
    }
    red[qr][nl][0] = l;
    red[qr][nl][1] = o0;
    red[qr][nl][2] = o1;
    __syncthreads();

    if (t < 64) {
        const int nn = tile * 64 + t;
        float L = red[0][t][0] + red[1][t][0] + red[2][t][0] + red[3][t][0];
        float O0 = red[0][t][1] + red[1][t][1] + red[2][t][1] + red[3][t][1];
        float O1 = red[0][t][2] + red[1][t][2] + red[2][t][2] + red[3][t][2];
        const float rl = 1.f / L;
        aout[(size_t)b * 2048 + nn * 8 + 2 * h]     = O0 * rl;
        aout[(size_t)b * 2048 + nn * 8 + 2 * h + 1] = O1 * rl;
    }
}

// ---------------- K3c: proj+res, LN, MLP+res, GN2 stats (pre-upsample) + SiLU ----------------
// grid 16 = B, block 256 (one thread per pixel n)
__global__ __launch_bounds__(256) void k3c_post(
    const float* __restrict__ z0, const float* __restrict__ aout,
    const float* __restrict__ w_proj, const float* __restrict__ b_proj,
    const float* __restrict__ ln_g, const float* __restrict__ ln_b,
    const float* __restrict__ w_fc1, const float* __restrict__ b_fc1,
    const float* __restrict__ w_fc2, const float* __restrict__ b_fc2,
    const float* __restrict__ g2, const float* __restrict__ b2,
    float* __restrict__ a2)
{
    const int b = blockIdx.x, t = threadIdx.x;
    const int wid = t >> 6, lane = t & 63;

    __shared__ float zsh[8][256];
    __shared__ float stats[16];

#pragma unroll
    for (int c = 0; c < 8; ++c) zsh[c][t] = z0[(size_t)b * 2048 + c * 256 + t];

    // per-pixel attention output (8 contiguous floats)
    const float4 ao0 = *reinterpret_cast<const float4*>(aout + (size_t)b * 2048 + t * 8);
    const float4 ao1 = *reinterpret_cast<const float4*>(aout + (size_t)b * 2048 + t * 8 + 4);
    const float ao[8] = {ao0.x, ao0.y, ao0.z, ao0.w, ao1.x, ao1.y, ao1.z, ao1.w};
    __syncthreads();

    // proj + residual
    float z1[8];
#pragma unroll
    for (int o = 0; o < 8; ++o) {
        float acc = b_proj[o];
#pragma unroll
        for (int c = 0; c < 8; ++c) acc += w_proj[o * 8 + c] * ao[c];
        z1[o] = zsh[o][t] + acc;
    }

    // LayerNorm over 8 channels (per pixel)
    float mu = 0.f;
#pragma unroll
    for (int c = 0; c < 8; ++c) mu += z1[c];
    mu *= (1.f / 8.f);
    float var = 0.f;
#pragma unroll
    for (int c = 0; c < 8; ++c) { const float d = z1[c] - mu; var += d * d; }
    var *= (1.f / 8.f);
    const float linv = rsqrtf(var + EPSV);
    float ln[8];
#pragma unroll
    for (int c = 0; c < 8; ++c) ln[c] = (z1[c] - mu) * linv * ln_g[c] + ln_b[c];

    // fc1 + exact gelu
    float hg[16];
#pragma unroll
    for (int o = 0; o < 16; ++o) {
        float hv = b_fc1[o];
#pragma unroll
        for (int c = 0; c < 8; ++c) hv += w_fc1[o * 8 + c] * ln[c];
        hg[o] = 0.5f * hv * (1.f + erff(hv * 0.70710678f));
    }
    // fc2 + residual
    float z2[8];
#pragma unroll
    for (int c = 0; c < 8; ++c) {
        float acc = b_fc2[c];
#pragma unroll
        for (int o = 0; o < 16; ++o) acc += w_fc2[c * 16 + o] * hg[o];
        z2[c] = z1[c] + acc;
    }

    // GN2 stats on pre-upsample map (repeat preserves mean/var), then SiLU
    __syncthreads();
#pragma unroll
    for (int c = 0; c < 8; ++c) zsh[c][t] = z2[c];
    __syncthreads();
#pragma unroll
    for (int cc = 0; cc < 2; ++cc) {
        const int c = wid * 2 + cc;
        const float a0 = zsh[c][lane], a1v = zsh[c][lane + 64], a2v = zsh[c][lane + 128], a3v = zsh[c][lane + 192];
        float s = a0 + a1v + a2v + a3v;
        float ss = a0 * a0 + a1v * a1v + a2v * a2v + a3v * a3v;
#pragma unroll
        for (int off = 32; off; off >>= 1) {
            s += __shfl_down(s, off);
            ss += __shfl_down(ss, off);
        }
        if (lane == 0) {
            const float m = s * (1.f / 256.f);
            const float vv = ss * (1.f / 256.f) - m * m;
            stats[2 * c] = m;
            stats[2 * c + 1] = rsqrtf(vv + EPSV);
        }
    }
    __syncthreads();
#pragma unroll
    for (int c = 0; c < 8; ++c) {
        const float xn = (z2[c] - stats[2 * c]) * stats[2 * c + 1] * g2[c] + b2[c];
        a2[(size_t)b * 2048 + c * 256 + t] = xn / (1.f + __expf(-xn));
    }
}

// ---------------- K4: upsample-on-the-fly conv3x3 8->320 on 64x64 ----------------
// Upsampled input is piecewise-constant over 4x4 cells: the 16 outputs per
// cell take only 9 distinct values. ~25 FMA + ~24 adds per channel vs 144 FMA.
// grid (320, 16) = (out-channel, batch), block 256 (one thread per 4x4 cell)
__global__ __launch_bounds__(256) void k4_conv2(
    const float* __restrict__ a2, const float* __restrict__ w2,
    const float* __restrict__ bc2, float* __restrict__ out)
{
    const int o = blockIdx.x, b = blockIdx.y, t = threadIdx.x;
    __shared__ float A[8 * 324];   // (8, 18, 18) zero-halo padded pooled map
    __shared__ float wsh[72];

    for (int i = t; i < 2592; i += 256) A[i] = 0.f;
    if (t < 72) wsh[t] = w2[o * 72 + t];
    __syncthreads();
    for (int i = t; i < 2048; i += 256) {
        const int c = i >> 8, y = (i >> 4) & 15, x = i & 15;
        A[c * 324 + (y + 1) * 18 + (x + 1)] = a2[(size_t)b * 2048 + i];
    }
    __syncthreads();

    const int cy = t >> 4, cx = t & 15;
    const float bias = bc2[o];
    float acc[3][3];
#pragma unroll
    for (int r = 0; r < 3; ++r)
#pragma unroll
        for (int s = 0; s < 3; ++s) acc[r][s] = bias;

    const float* Abase = &A[cy * 18 + cx];
#pragma unroll
    for (int c = 0; c < 8; ++c) {
        const float C00 = Abase[c * 324 + 0 * 18 + 0], C01 = Abase[c * 324 + 0 * 18 + 1], C02 = Abase[c * 324 + 0 * 18 + 2];
        const float C10 = Abase[c * 324 + 1 * 18 + 0], C11 = Abase[c * 324 + 1 * 18 + 1], C12 = Abase[c * 324 + 1 * 18 + 2];
        const float C20 = Abase[c * 324 + 2 * 18 + 0], C21 = Abase[c * 324 + 2 * 18 + 1], C22 = Abase[c * 324 + 2 * 18 + 2];

        const float k0 = wsh[c * 9 + 0], k1 = wsh[c * 9 + 1], k2 = wsh[c * 9 + 2];
        const float k3 = wsh[c * 9 + 3], k4 = wsh[c * 9 + 4], k5 = wsh[c * 9 + 5];
        const float k6 = wsh[c * 9 + 6], k7 = wsh[c * 9 + 7], k8 = wsh[c * 9 + 8];

        const float q12x = k3 + k6, q12y = k4 + k7, q12z = k5 + k8;
        const float q01x = k0 + k3, q01y = k1 + k4, q01z = k2 + k5;
        const float qax = q12x + k0, qay = q12y + k1, qaz = q12z + k2;

        const float r0_c12 = k1 + k2,      r0_c012 = r0_c12 + k0,     r0_c01 = k0 + k1;
        const float q12_c12 = q12y + q12z, q12_c012 = q12_c12 + q12x, q12_c01 = q12x + q12y;
        const float qa_c12 = qay + qaz,    qa_c012 = qa_c12 + qax,    qa_c01 = qax + qay;
        const float q01_c12 = q01y + q01z, q01_c012 = q01_c12 + q01x, q01_c01 = q01x + q01y;
        const float r2_c12 = k7 + k8,      r2_c012 = r2_c12 + k6,     r2_c01 = k6 + k7;

        acc[0][0] += k0 * C00 + r0_c12 * C01 + q12x * C10 + q12_c12 * C11;
        acc[0][1] += r0_c012 * C01 + q12_c012 * C11;
        acc[0][2] += r0_c01 * C01 + k2 * C02 + q12_c01 * C11 + q12z * C12;
        acc[1][0] += qax * C10 + qa_c12 * C11;
        acc[1][1] += qa_c012 * C11;
        acc[1][2] += qa_c01 * C11 + qaz * C12;
        acc[2][0] += q01x * C10 + q01_c12 * C11 + k6 * C20 + r2_c12 * C21;
        acc[2][1] += q01_c012 * C11 + r2_c012 * C21;
        acc[2][2] += q01_c01 * C11 + q01z * C12 + r2_c01 * C21 + k8 * C22;
    }

    const size_t base = ((size_t)(b * 320 + o)) * 4096;
    const int rowmap[4] = {0, 1, 1, 2};
#pragma unroll
    for (int py = 0; py < 4; ++py) {
        const int r = rowmap[py];
        const float4 v = make_float4(acc[r][0], acc[r][1], acc[r][1], acc[r][2]);
        *reinterpret_cast<float4*>(out + base + (cy * 4 + py) * 64 + cx * 4) = v;
    }
}

extern "C" void kernel_launch(void* const* d_in, const int* in_sizes, int n_in,
                              void* d_out, int out_size, void* d_ws, size_t ws_size,
                              hipStream_t stream) {
    const float* x       = (const float*)d_in[0];
    const float* g1      = (const float*)d_in[1];
    const float* b1      = (const float*)d_in[2];
    const float* w_conv1 = (const float*)d_in[3];
    const float* b_conv1 = (const float*)d_in[4];
    const float* ga      = (const float*)d_in[5];
    const float* ba      = (const float*)d_in[6];
    const float* w_qkv   = (const float*)d_in[7];
    const float* b_qkv   = (const float*)d_in[8];
    const float* w_proj  = (const float*)d_in[9];
    const float* b_proj  = (const float*)d_in[10];
    const float* ln_g    = (const float*)d_in[11];
    const float* ln_b    = (const float*)d_in[12];
    const float* w_fc1   = (const float*)d_in[13];
    const float* b_fc1   = (const float*)d_in[14];
    const float* w_fc2   = (const float*)d_in[15];
    const float* b_fc2   = (const float*)d_in[16];
    const float* g2      = (const float*)d_in[17];
    const float* b2      = (const float*)d_in[18];
    const float* w_conv2 = (const float*)d_in[19];
    const float* b_conv2 = (const float*)d_in[20];

    float* a1   = (float*)d_ws;           // 1,310,720 floats
    float* z0   = a1 + 1310720;           //    32,768
    float* a2   = z0 + 32768;             //    32,768
    float* qsf  = a2 + 32768;             //    32,768 (16*4*256 float2)
    float* kvf  = qsf + 32768;            //    65,536 (16*4*256 float4)
    float* aout = kvf + 65536;            //    32,768
    float* out = (float*)d_out;

    k1_pool_gn1<<<512, 256, 0, stream>>>(x, g1, b1, b_conv1, a1, z0);
    k2_conv1<<<256, 256, 0, stream>>>(a1, w_conv1, z0);
    k3a_qkv<<<16, 256, 0, stream>>>(z0, ga, ba, w_qkv, b_qkv, (float2*)qsf, (float4*)kvf);
    k3b_attn<<<256, 256, 0, stream>>>((const float2*)qsf, (const float4*)kvf, aout);
    k3c_post<<<16, 256, 0, stream>>>(z0, aout, w_proj, b_proj, ln_g, ln_b,
                                     w_fc1, b_fc1, w_fc2, b_fc2, g2, b2, a2);
    k4_conv2<<<dim3(320, 16), 256, 0, stream>>>(a2, w_conv2, b_conv2, out);
}